// Round 1
// baseline (161.277 us; speedup 1.0000x reference)
//
#include <hip/hip_runtime.h>

#define BH 32
#define L  1024
#define D  64

typedef short  short8  __attribute__((ext_vector_type(8)));
typedef __bf16 bf16x8  __attribute__((ext_vector_type(8)));
typedef float  f32x16  __attribute__((ext_vector_type(16)));

__device__ __forceinline__ unsigned short f2bf(float f) {
    union { float f; unsigned u; } v; v.f = f;
    unsigned r = v.u + 0x7fffu + ((v.u >> 16) & 1u);   // RNE
    return (unsigned short)(r >> 16);
}

// ---------------------------------------------------------------------------
// Kernel 1: projections.  Xs = (X @ W1^T + b1) * w2 ; Yf = (Y @ W1^T + b1)
// stored bf16 in workspace.  blockIdx.y selects X vs Y; block does 128 rows.
// ---------------------------------------------------------------------------
__global__ __launch_bounds__(256, 4) void proj_kernel(
    const float* __restrict__ X, const float* __restrict__ Y,
    const float* __restrict__ W1, const float* __restrict__ b1,
    const float* __restrict__ w2,
    unsigned short* __restrict__ Xs, unsigned short* __restrict__ Yf)
{
    __shared__ unsigned short Wl[64 * 72];    // W1 bf16, row-major, pad 72
    __shared__ unsigned short Al[128 * 72];   // 128 input rows bf16, pad 72

    const int tid = threadIdx.x;
    const bool isX = (blockIdx.y == 0);
    const float* src = isX ? X : Y;
    unsigned short* dst = isX ? Xs : Yf;
    const int r0 = blockIdx.x * 128;          // global row (bh*L + i), 0..32640

    // stage W1 (64x64 fp32) -> bf16 LDS
    {
        const int d  = tid >> 2;
        const int kb = (tid & 3) * 16;
        const float4* wp = (const float4*)(W1 + d * 64 + kb);
        #pragma unroll
        for (int q = 0; q < 4; ++q) {
            float4 v = wp[q];
            unsigned short* o = &Wl[d * 72 + kb + q * 4];
            o[0] = f2bf(v.x); o[1] = f2bf(v.y); o[2] = f2bf(v.z); o[3] = f2bf(v.w);
        }
    }
    // stage 128 rows of X/Y (contiguous 32 KB) -> bf16 LDS
    {
        const float4* xp = (const float4*)(src + (size_t)r0 * 64);
        #pragma unroll
        for (int p = 0; p < 8; ++p) {
            int c = tid + 256 * p;            // float4 chunk 0..2047
            float4 v = xp[c];
            int row = c >> 4;                 // 16 float4 per 64-elem row
            int c4  = (c & 15) * 4;
            unsigned short* o = &Al[row * 72 + c4];
            o[0] = f2bf(v.x); o[1] = f2bf(v.y); o[2] = f2bf(v.z); o[3] = f2bf(v.w);
        }
    }
    __syncthreads();

    const int w   = tid >> 6;                 // wave 0..3 -> rows w*32..+31
    const int l   = tid & 63;
    const int l31 = l & 31;
    const int lh  = l >> 5;

    f32x16 acc[2] = {};

    const int arow = w * 32 + l31;
    #pragma unroll
    for (int kk = 0; kk < 4; ++kk) {
        int k0 = kk * 16 + lh * 8;
        bf16x8 a = *(const bf16x8*)&Al[arow * 72 + k0];
        #pragma unroll
        for (int nt = 0; nt < 2; ++nt) {
            bf16x8 b = *(const bf16x8*)&Wl[(nt * 32 + l31) * 72 + k0];
            acc[nt] = __builtin_amdgcn_mfma_f32_32x32x16_bf16(a, b, acc[nt], 0, 0, 0);
        }
    }

    #pragma unroll
    for (int nt = 0; nt < 2; ++nt) {
        int d = nt * 32 + l31;
        float bb = b1[d];
        float ww = isX ? w2[d] : 1.0f;
        #pragma unroll
        for (int r = 0; r < 16; ++r) {
            int row = w * 32 + 4 * lh + (r & 3) + 8 * (r >> 2);
            float v = (acc[nt][r] + bb) * ww;
            dst[(size_t)(r0 + row) * 64 + d] = f2bf(v);
        }
    }
}

// ---------------------------------------------------------------------------
// Kernel 2: per-bh TN GEMM, C = relu(Xs @ Yf^T + b2), M=N=1024, K=64.
// 128x128 block tile, 4 waves (2x2), each wave 2x2 accs of 32x32x16 MFMA.
// ---------------------------------------------------------------------------
__global__ __launch_bounds__(256, 4) void score_kernel(
    const unsigned short* __restrict__ Xs, const unsigned short* __restrict__ Yf,
    const float* __restrict__ b2p, float* __restrict__ out)
{
    __shared__ unsigned short As[128 * 72];
    __shared__ unsigned short Bs[128 * 72];

    const int tid = threadIdx.x;
    const int bh  = blockIdx.z;
    const int i0  = blockIdx.y * 128;
    const int j0  = blockIdx.x * 128;

    const unsigned short* aSrc = Xs + ((size_t)bh * L + i0) * D;  // 16 KB contiguous
    const unsigned short* bSrc = Yf + ((size_t)bh * L + j0) * D;

    // stage both 128x64 bf16 tiles (each contiguous 16 KB) into padded LDS
    #pragma unroll
    for (int p = 0; p < 4; ++p) {
        int c   = tid + 256 * p;             // 16B chunk 0..1023
        int row = c >> 3;                    // 8 chunks per 64-elem row
        int col = c & 7;
        short8 va = *(const short8*)(aSrc + (size_t)c * 8);
        short8 vb = *(const short8*)(bSrc + (size_t)c * 8);
        *(short8*)&As[row * 72 + col * 8] = va;
        *(short8*)&Bs[row * 72 + col * 8] = vb;
    }
    __syncthreads();

    const int w    = tid >> 6;
    const int l    = tid & 63;
    const int l31  = l & 31;
    const int lh   = l >> 5;
    const int wrow = (w >> 1) * 64;
    const int wcol = (w & 1) * 64;

    f32x16 acc[2][2] = {};

    #pragma unroll
    for (int kk = 0; kk < 4; ++kk) {
        int k0 = kk * 16 + lh * 8;
        bf16x8 a0 = *(const bf16x8*)&As[(wrow +      l31) * 72 + k0];
        bf16x8 a1 = *(const bf16x8*)&As[(wrow + 32 + l31) * 72 + k0];
        bf16x8 b0 = *(const bf16x8*)&Bs[(wcol +      l31) * 72 + k0];
        bf16x8 b1 = *(const bf16x8*)&Bs[(wcol + 32 + l31) * 72 + k0];
        acc[0][0] = __builtin_amdgcn_mfma_f32_32x32x16_bf16(a0, b0, acc[0][0], 0, 0, 0);
        acc[0][1] = __builtin_amdgcn_mfma_f32_32x32x16_bf16(a0, b1, acc[0][1], 0, 0, 0);
        acc[1][0] = __builtin_amdgcn_mfma_f32_32x32x16_bf16(a1, b0, acc[1][0], 0, 0, 0);
        acc[1][1] = __builtin_amdgcn_mfma_f32_32x32x16_bf16(a1, b1, acc[1][1], 0, 0, 0);
    }

    const float b2 = b2p[0];
    float* obase = out + (size_t)bh * L * L;

    #pragma unroll
    for (int ti = 0; ti < 2; ++ti) {
        #pragma unroll
        for (int tj = 0; tj < 2; ++tj) {
            int gj = j0 + wcol + tj * 32 + l31;
            #pragma unroll
            for (int r = 0; r < 16; ++r) {
                int gi = i0 + wrow + ti * 32 + 4 * lh + (r & 3) + 8 * (r >> 2);
                float v = acc[ti][tj][r] + b2;
                v = v > 0.0f ? v : 0.0f;
                obase[(size_t)gi * L + gj] = v;
            }
        }
    }
}

extern "C" void kernel_launch(void* const* d_in, const int* in_sizes, int n_in,
                              void* d_out, int out_size, void* d_ws, size_t ws_size,
                              hipStream_t stream) {
    (void)in_sizes; (void)n_in; (void)out_size; (void)ws_size;
    const float* X  = (const float*)d_in[0];
    const float* Y  = (const float*)d_in[1];
    const float* W1 = (const float*)d_in[2];
    const float* b1 = (const float*)d_in[3];
    const float* w2 = (const float*)d_in[4];
    const float* b2 = (const float*)d_in[5];
    float* out = (float*)d_out;

    unsigned short* Xs = (unsigned short*)d_ws;               // 32*1024*64 bf16 = 4 MB
    unsigned short* Yf = Xs + (size_t)BH * L * D;             // + 4 MB

    dim3 pgrid(256, 2, 1);                                    // 256 blocks x {X,Y}
    proj_kernel<<<pgrid, 256, 0, stream>>>(X, Y, W1, b1, w2, Xs, Yf);

    dim3 ggrid(8, 8, BH);                                     // j-tiles, i-tiles, bh
    score_kernel<<<ggrid, 256, 0, stream>>>(Xs, Yf, b2, out);
}